// Round 6
// baseline (195.172 us; speedup 1.0000x reference)
//
#include <hip/hip_runtime.h>

// Problem constants: B=1, T=4096, C=512, H=8, HS=64
#define T_ 4096
#define C_ 512
#define H_ 8
#define HS_ 64

typedef __attribute__((ext_vector_type(8))) short s16x8;   // 8 x bf16 bits
typedef __attribute__((ext_vector_type(4))) float f32x4;
typedef unsigned int u32;

__device__ __forceinline__ float bf2f(short u) {
    union { float f; unsigned int i; } v;
    v.i = ((unsigned int)(unsigned short)u) << 16;
    return v.f;
}
__device__ __forceinline__ short f2bf(float f) {
    union { float f; unsigned int i; } v;
    v.f = f;
    unsigned int r = (v.i + 0x7FFFu + ((v.i >> 16) & 1u)) >> 16;
    return (short)r;
}

__device__ __forceinline__ void gload_lds16(const short* g, short* l) {
    __builtin_amdgcn_global_load_lds((const __attribute__((address_space(1))) u32*)g,
                                     (__attribute__((address_space(3))) u32*)l,
                                     16, 0, 0);
}

// ---------------- merged f32 -> bf16 convert (x, W_attn, W_proj) ----------------
__global__ void cvt3_kernel(const float* __restrict__ x, const float* __restrict__ wa,
                            const float* __restrict__ wp,
                            short* __restrict__ xb, short* __restrict__ wab,
                            short* __restrict__ wpb) {
    int b = blockIdx.x, tid = threadIdx.x;
    const float* src; short* dst; int i;
    if (b < 2048)      { src = x;  dst = xb;  i = b * 256 + tid; }
    else if (b < 2816) { src = wa; dst = wab; i = (b - 2048) * 256 + tid; }
    else               { src = wp; dst = wpb; i = (b - 2816) * 256 + tid; }
    float4 v = ((const float4*)src)[i];
    short4 o;
    o.x = f2bf(v.x); o.y = f2bf(v.y); o.z = f2bf(v.z); o.w = f2bf(v.w);
    ((short4*)dst)[i] = o;
}

// ---------------- GEMM: C[m][n] = sum_k A[m][k] * B[n][k] (B given transposed) ----
// BMxBN tile, BK=64, 256 threads (4 waves 2x2), global_load_lds x16,
// XOR-swizzled LDS (pre-swizzled global source) -> 2-way banks on ds_read_b128.
template <int BM, int BN, int OUT_BF16>
__global__ __launch_bounds__(256) void gemm_bt(const short* __restrict__ A,
                                               const short* __restrict__ B,
                                               void* __restrict__ Cv,
                                               int M, int N, int K) {
    __shared__ __align__(16) short As[BM][64];
    __shared__ __align__(16) short Bs[BN][64];
    constexpr int WM = BM / 2, WN = BN / 2;
    constexpr int MR = WM / 16, NR = WN / 16;
    int bn = blockIdx.x, bm = blockIdx.y;
    int tid = threadIdx.x;
    int lane = tid & 63, w = tid >> 6;
    int wr = w >> 1, wc = w & 1;
    int lr = lane & 15, lg = lane >> 4;

    f32x4 acc[MR][NR];
#pragma unroll
    for (int m = 0; m < MR; ++m)
#pragma unroll
        for (int n = 0; n < NR; ++n) acc[m][n] = f32x4{0.f, 0.f, 0.f, 0.f};

    const short* Ab = A + (size_t)bm * BM * K;
    const short* Bb = B + (size_t)bn * BN * K;

    for (int k0 = 0; k0 < K; k0 += 64) {
#pragma unroll
        for (int i = 0; i < BM / 32; ++i) {
            int c = i * 256 + tid;
            int row = c >> 3, cb = (c & 7) ^ (row & 7);
            gload_lds16(Ab + (size_t)row * K + k0 + cb * 8, &As[0][0] + c * 8);
        }
#pragma unroll
        for (int i = 0; i < BN / 32; ++i) {
            int c = i * 256 + tid;
            int row = c >> 3, cb = (c & 7) ^ (row & 7);
            gload_lds16(Bb + (size_t)row * K + k0 + cb * 8, &Bs[0][0] + c * 8);
        }
        __syncthreads();
#pragma unroll
        for (int kk = 0; kk < 2; ++kk) {
            s16x8 af[MR], bf[NR];
#pragma unroll
            for (int m = 0; m < MR; ++m) {
                int row = wr * WM + m * 16 + lr;
                af[m] = *(const s16x8*)&As[row][(((kk * 4 + lg) ^ (row & 7)) << 3)];
            }
#pragma unroll
            for (int n = 0; n < NR; ++n) {
                int row = wc * WN + n * 16 + lr;
                bf[n] = *(const s16x8*)&Bs[row][(((kk * 4 + lg) ^ (row & 7)) << 3)];
            }
#pragma unroll
            for (int m = 0; m < MR; ++m)
#pragma unroll
                for (int n = 0; n < NR; ++n)
                    acc[m][n] = __builtin_amdgcn_mfma_f32_16x16x32_bf16(af[m], bf[n], acc[m][n], 0, 0, 0);
        }
        __syncthreads();
    }

#pragma unroll
    for (int m = 0; m < MR; ++m) {
        int row = bm * BM + wr * WM + m * 16 + lg * 4;
#pragma unroll
        for (int n = 0; n < NR; ++n) {
            int col = bn * BN + wc * WN + n * 16 + lr;
#pragma unroll
            for (int i = 0; i < 4; ++i) {
                size_t idx = (size_t)(row + i) * N + col;
                if (OUT_BF16) ((short*)Cv)[idx] = f2bf(acc[m][n][i]);
                else          ((float*)Cv)[idx] = acc[m][n][i];
            }
        }
    }
}

// ------- fused RoPE (q,k) + V transpose; block = (64 t-rows, head) -------
// q pre-scaled by 0.125 * log2(e): attention runs in exp2 domain.
__global__ __launch_bounds__(256) void prep_kernel(const short* __restrict__ qkv,
                                                   const float* __restrict__ rope,
                                                   short* __restrict__ q,
                                                   short* __restrict__ k,
                                                   short* __restrict__ vt) {
    __shared__ short tile[64][72];
    int bt = blockIdx.x, h = blockIdx.y;
    int tid = threadIdx.x;
    const float QS = 0.18033688011112042f;   // 0.125 * log2(e)

#pragma unroll
    for (int r = 0; r < 2; ++r) {
        int idx = r * 256 + tid;
        int tt = idx >> 3, c8 = idx & 7;
        int t = bt * 64 + tt;
        const short* row = qkv + (size_t)t * (3 * C_) + h * 64 + c8 * 8;
        s16x8 qv = *(const s16x8*)row;
        s16x8 kv = *(const s16x8*)(row + C_);
        float4 rc0 = *(const float4*)(rope + t * 64 + c8 * 8);
        float4 rc1 = *(const float4*)(rope + t * 64 + c8 * 8 + 4);
        float cs[4] = {rc0.x, rc0.z, rc1.x, rc1.z};
        float sn[4] = {rc0.y, rc0.w, rc1.y, rc1.w};
        s16x8 qo, ko;
#pragma unroll
        for (int p = 0; p < 4; ++p) {
            float qe = bf2f(qv[2 * p]), qd = bf2f(qv[2 * p + 1]);
            float ke = bf2f(kv[2 * p]), kd = bf2f(kv[2 * p + 1]);
            qo[2 * p]     = f2bf((qe * cs[p] - qd * sn[p]) * QS);
            qo[2 * p + 1] = f2bf((qd * cs[p] + qe * sn[p]) * QS);
            ko[2 * p]     = f2bf(ke * cs[p] - kd * sn[p]);
            ko[2 * p + 1] = f2bf(kd * cs[p] + ke * sn[p]);
        }
        size_t o = ((size_t)h * T_ + t) * HS_ + c8 * 8;
        *(s16x8*)(q + o) = qo;
        *(s16x8*)(k + o) = ko;
    }

    // V transpose through LDS
#pragma unroll
    for (int it = 0; it < 16; ++it) {
        int idx = it * 256 + tid;
        int dd = idx & 63, tt = idx >> 6;
        tile[tt][dd] = qkv[(size_t)(bt * 64 + tt) * (3 * C_) + 2 * C_ + h * 64 + dd];
    }
    __syncthreads();
#pragma unroll
    for (int it = 0; it < 16; ++it) {
        int idx = it * 256 + tid;
        int tt = idx & 63, dd = idx >> 6;
        vt[((size_t)h * HS_ + dd) * T_ + bt * 64 + tt] = tile[tt][dd];
    }
}

// ---------------- Flash attention: constant-M softmax, balanced split-K --------
// Grid = 1152 blocks = 8 heads x 144 (qb,chunk) units; head = bx&7 (XCD pin).
// Per 128-row block qb: tiles = 2qb+2 split into ceil((qb+1)/4) equal chunks.
// Block: 4 waves x 32 rows (2 Q-frags). K,V in LDS (dbuf, XOR-swizzle);
// single per-wave P buffer (A then B frag); l via ones-MFMA.
// p = exp2(s - 12): shift-invariance makes combine a plain sum.
__global__ __launch_bounds__(256) void attn_kernel(const short* __restrict__ q,
                                                   const short* __restrict__ k,
                                                   const short* __restrict__ vt,
                                                   short* __restrict__ ypart,
                                                   float* __restrict__ lpart) {
    __shared__ __align__(16) short Ks[2][64][64];   // 16 KB
    __shared__ __align__(16) short Vs[2][64][64];   // 16 KB
    __shared__ __align__(16) short P[4][16][64];    // 8 KB (A/B reuse)
    int bx = blockIdx.x;
    int h = bx & 7;                    // head -> XCD pin
    int u = bx >> 3;                   // 0..143, heavy qb first
    int qb = 0, j = u;
    for (int qq = 31; qq >= 0; --qq) {
        int ncq = (qq + 4) >> 2;       // ceil((qq+1)/4)
        if (j < ncq) { qb = qq; break; }
        j -= ncq;
    }
    int ncq = (qb + 4) >> 2;
    int tiles = 2 * qb + 2;
    int bas = tiles / ncq, rr = tiles % ncq;
    int t0 = j * bas + (j < rr ? j : rr);
    int t1 = t0 + bas + (j < rr ? 1 : 0);

    int tid = threadIdx.x;
    int w = tid >> 6, lane = tid & 63;
    int lr = lane & 15, lg = lane >> 4, x7 = lane & 7;
    int qrow0 = qb * 128 + w * 32;
    const float MC = 12.0f;            // constant max (log2 domain)

    const short* qp = q + ((size_t)h * T_ + qrow0 + lr) * HS_ + lg * 8;
    s16x8 aq0 = *(const s16x8*)qp;
    s16x8 aq1 = *(const s16x8*)(qp + 32);
    s16x8 aq2 = *(const s16x8*)(qp + 16 * HS_);
    s16x8 aq3 = *(const s16x8*)(qp + 16 * HS_ + 32);

    s16x8 bones;
#pragma unroll
    for (int jj = 0; jj < 8; ++jj) bones[jj] = (short)0x3F80;   // bf16 1.0

    f32x4 yA[4], yB[4];
#pragma unroll
    for (int n = 0; n < 4; ++n) { yA[n] = f32x4{0.f,0.f,0.f,0.f}; yB[n] = f32x4{0.f,0.f,0.f,0.f}; }
    f32x4 lAa = f32x4{0.f,0.f,0.f,0.f}, lBa = f32x4{0.f,0.f,0.f,0.f};

    const short* kH = k + (size_t)h * T_ * HS_;
    const short* vH = vt + (size_t)h * HS_ * T_;

    auto stage = [&](short* Kb, short* Vb, int t) {
#pragma unroll
        for (int r = 0; r < 2; ++r) {
            int c = r * 256 + tid;
            int row = c >> 3;
            int cb = (c & 7) ^ (row & 7);      // inverse-swizzled source col-block
            gload_lds16(kH + (size_t)(t * 64 + row) * HS_ + cb * 8, Kb + c * 8);
            gload_lds16(vH + (size_t)row * T_ + t * 64 + cb * 8, Vb + c * 8);
        }
    };

    short* Pw = &P[w][0][0];

    auto body = [&](int t, const short* Kb, const short* Vb) {
        f32x4 sA[4], sB[4];
#pragma unroll
        for (int c4 = 0; c4 < 4; ++c4) {
            int krow = c4 * 16 + lr;
            const short* kp = Kb + krow * 64;
            s16x8 k0 = *(const s16x8*)(kp + ((lg ^ x7) << 3));
            s16x8 k1 = *(const s16x8*)(kp + (((lg + 4) ^ x7) << 3));
            f32x4 s = f32x4{0.f,0.f,0.f,0.f};
            s = __builtin_amdgcn_mfma_f32_16x16x32_bf16(aq0, k0, s, 0, 0, 0);
            sA[c4] = __builtin_amdgcn_mfma_f32_16x16x32_bf16(aq1, k1, s, 0, 0, 0);
            f32x4 s2 = f32x4{0.f,0.f,0.f,0.f};
            s2 = __builtin_amdgcn_mfma_f32_16x16x32_bf16(aq2, k0, s2, 0, 0, 0);
            sB[c4] = __builtin_amdgcn_mfma_f32_16x16x32_bf16(aq3, k1, s2, 0, 0, 0);
        }
        if (t * 64 + 63 > qrow0) {        // causal mask, frag A (rows qrow0..+15)
#pragma unroll
            for (int c4 = 0; c4 < 4; ++c4) {
                int kcol = t * 64 + c4 * 16 + lr;
#pragma unroll
                for (int i = 0; i < 4; ++i)
                    if (kcol > qrow0 + lg * 4 + i) sA[c4][i] = -1e30f;
            }
        }
        if (t * 64 + 63 > qrow0 + 16) {   // frag B (rows qrow0+16..+31)
#pragma unroll
            for (int c4 = 0; c4 < 4; ++c4) {
                int kcol = t * 64 + c4 * 16 + lr;
#pragma unroll
                for (int i = 0; i < 4; ++i)
                    if (kcol > qrow0 + 16 + lg * 4 + i) sB[c4][i] = -1e30f;
            }
        }
        // V fragments hoisted once (shared by A and B PV)
        s16x8 vf[8];
#pragma unroll
        for (int n = 0; n < 4; ++n) {
            int vrow = n * 16 + lr;
            const short* vrp = Vb + vrow * 64;
            vf[2 * n]     = *(const s16x8*)(vrp + ((lg ^ (vrow & 7)) << 3));
            vf[2 * n + 1] = *(const s16x8*)(vrp + (((lg + 4) ^ (vrow & 7)) << 3));
        }
        // ---- frag A: p = exp2(s-MC) -> P -> A-frag -> l + PV ----
#pragma unroll
        for (int c4 = 0; c4 < 4; ++c4)
#pragma unroll
            for (int i = 0; i < 4; ++i) {
                int row = lg * 4 + i;
                int off = row * 64 + (((c4 * 2 + (lr >> 3)) ^ (row & 7)) << 3) + (lr & 7);
                Pw[off] = f2bf(exp2f(sA[c4][i] - MC));
            }
        s16x8 ap0 = *(const s16x8*)&Pw[lr * 64 + ((lg ^ x7) << 3)];
        s16x8 ap1 = *(const s16x8*)&Pw[lr * 64 + (((lg + 4) ^ x7) << 3)];
        lAa = __builtin_amdgcn_mfma_f32_16x16x32_bf16(ap0, bones, lAa, 0, 0, 0);
        lAa = __builtin_amdgcn_mfma_f32_16x16x32_bf16(ap1, bones, lAa, 0, 0, 0);
#pragma unroll
        for (int n = 0; n < 4; ++n) {
            yA[n] = __builtin_amdgcn_mfma_f32_16x16x32_bf16(ap0, vf[2 * n], yA[n], 0, 0, 0);
            yA[n] = __builtin_amdgcn_mfma_f32_16x16x32_bf16(ap1, vf[2 * n + 1], yA[n], 0, 0, 0);
        }
        // ---- frag B (reuses P buffer) ----
#pragma unroll
        for (int c4 = 0; c4 < 4; ++c4)
#pragma unroll
            for (int i = 0; i < 4; ++i) {
                int row = lg * 4 + i;
                int off = row * 64 + (((c4 * 2 + (lr >> 3)) ^ (row & 7)) << 3) + (lr & 7);
                Pw[off] = f2bf(exp2f(sB[c4][i] - MC));
            }
        s16x8 bp0 = *(const s16x8*)&Pw[lr * 64 + ((lg ^ x7) << 3)];
        s16x8 bp1 = *(const s16x8*)&Pw[lr * 64 + (((lg + 4) ^ x7) << 3)];
        lBa = __builtin_amdgcn_mfma_f32_16x16x32_bf16(bp0, bones, lBa, 0, 0, 0);
        lBa = __builtin_amdgcn_mfma_f32_16x16x32_bf16(bp1, bones, lBa, 0, 0, 0);
#pragma unroll
        for (int n = 0; n < 4; ++n) {
            yB[n] = __builtin_amdgcn_mfma_f32_16x16x32_bf16(bp0, vf[2 * n], yB[n], 0, 0, 0);
            yB[n] = __builtin_amdgcn_mfma_f32_16x16x32_bf16(bp1, vf[2 * n + 1], yB[n], 0, 0, 0);
        }
    };

    // double-buffered pipeline (uniform trip count across waves)
    stage(&Ks[0][0][0], &Vs[0][0][0], t0);
    __syncthreads();
    int t = t0;
    for (;;) {
        bool m1 = (t + 1 < t1);
        if (m1) stage(&Ks[1][0][0], &Vs[1][0][0], t + 1);
        body(t, &Ks[0][0][0], &Vs[0][0][0]);
        __syncthreads();
        ++t;
        if (!m1) break;
        bool m2 = (t + 1 < t1);
        if (m2) stage(&Ks[0][0][0], &Vs[0][0][0], t + 1);
        body(t, &Ks[1][0][0], &Vs[1][0][0]);
        __syncthreads();
        ++t;
        if (!m2) break;
    }

    // write unnormalized bf16 partials + l
    short* yp = ypart + (((size_t)j * H_ + h) * T_ + qrow0) * HS_;
#pragma unroll
    for (int n = 0; n < 4; ++n)
#pragma unroll
        for (int i = 0; i < 4; ++i) {
            yp[(size_t)(lg * 4 + i) * HS_ + n * 16 + lr]      = f2bf(yA[n][i]);
            yp[(size_t)(16 + lg * 4 + i) * HS_ + n * 16 + lr] = f2bf(yB[n][i]);
        }
    if (lr == 0) {
#pragma unroll
        for (int i = 0; i < 4; ++i) {
            size_t r = ((size_t)j * H_ + h) * T_ + qrow0;
            lpart[r + lg * 4 + i]      = lAa[i];
            lpart[r + 16 + lg * 4 + i] = lBa[i];
        }
    }
}

// ---------------- combine partials (plain sums) -> yws bf16 [T][C] ----------------
__global__ void combine_kernel(const short* __restrict__ ypart,
                               const float* __restrict__ lpart,
                               short* __restrict__ y) {
    int g = blockIdx.x * 256 + threadIdx.x;   // 8h * 4096row * 8c8 = 262144
    int c8 = (g & 7) * 8;
    int row = (g >> 3) & 4095;
    int h = g >> 15;
    int nc = ((row >> 7) + 4) >> 2;           // chunks for this row's qb
    float L = 0.f;
    float acc[8] = {0.f, 0.f, 0.f, 0.f, 0.f, 0.f, 0.f, 0.f};
    for (int c = 0; c < nc; ++c) {
        size_t base = ((size_t)c * H_ + h) * T_ + row;
        L += lpart[base];
        s16x8 yv = *(const s16x8*)(ypart + base * HS_ + c8);
#pragma unroll
        for (int jj = 0; jj < 8; ++jj) acc[jj] += bf2f(yv[jj]);
    }
    float inv = 1.f / L;
    s16x8 o;
#pragma unroll
    for (int jj = 0; jj < 8; ++jj) o[jj] = f2bf(acc[jj] * inv);
    *(s16x8*)(y + (size_t)row * C_ + h * 64 + c8) = o;
}

// ---------------- launch ----------------
extern "C" void kernel_launch(void* const* d_in, const int* in_sizes, int n_in,
                              void* d_out, int out_size, void* d_ws, size_t ws_size,
                              hipStream_t stream) {
    const float* x    = (const float*)d_in[0];
    const float* rope = (const float*)d_in[1];
    // d_in[2] = mask (bool) — causality handled analytically
    const float* Wa   = (const float*)d_in[3];
    const float* Wp   = (const float*)d_in[4];
    float* out = (float*)d_out;

    short* ws   = (short*)d_ws;
    short* xb   = ws;                          // 4096*512
    short* wab  = xb + 2097152;                // 1536*512
    short* wpb  = wab + 786432;                // 512*512
    short* qkvb = wpb + 262144;                // 4096*1536
    short* qws  = qkvb + 6291456;              // 8*4096*64
    short* kws  = qws + 2097152;
    short* vtws = kws + 2097152;
    short* yws  = vtws + 2097152;              // 4096*512
    short* ypart = yws + 2097152;              // [8][8][4096][64] bf16 = 33.5 MB
    float* lpart = (float*)(ypart + 16777216); // [8][8][4096] f32 = 1 MB

    cvt3_kernel<<<3072, 256, 0, stream>>>(x, Wa, Wp, xb, wab, wpb);

    gemm_bt<128, 128, 1><<<dim3(12, 32), 256, 0, stream>>>(xb, wab, qkvb, 4096, 1536, 512);

    prep_kernel<<<dim3(64, 8), 256, 0, stream>>>(qkvb, rope, qws, kws, vtws);

    attn_kernel<<<1152, 256, 0, stream>>>(qws, kws, vtws, ypart, lpart);
    combine_kernel<<<1024, 256, 0, stream>>>(ypart, lpart, yws);

    gemm_bt<128, 64, 0><<<dim3(8, 32), 256, 0, stream>>>(yws, wpb, out, 4096, 512, 512);
}

// Round 8
// 181.396 us; speedup vs baseline: 1.0759x; 1.0759x over previous
//
#include <hip/hip_runtime.h>

// Problem constants: B=1, T=4096, C=512, H=8, HS=64
#define T_ 4096
#define C_ 512
#define H_ 8
#define HS_ 64

typedef __attribute__((ext_vector_type(8))) short s16x8;   // 8 x bf16 bits
typedef __attribute__((ext_vector_type(4))) float f32x4;
typedef unsigned int u32;

__device__ __forceinline__ float bf2f(short u) {
    union { float f; unsigned int i; } v;
    v.i = ((unsigned int)(unsigned short)u) << 16;
    return v.f;
}
__device__ __forceinline__ short f2bf(float f) {
    union { float f; unsigned int i; } v;
    v.f = f;
    unsigned int r = (v.i + 0x7FFFu + ((v.i >> 16) & 1u)) >> 16;
    return (short)r;
}

__device__ __forceinline__ void gload_lds16(const short* g, short* l) {
    __builtin_amdgcn_global_load_lds((const __attribute__((address_space(1))) u32*)g,
                                     (__attribute__((address_space(3))) u32*)l,
                                     16, 0, 0);
}

// ---------------- merged f32 -> bf16 convert (x, W_attn, W_proj) ----------------
__global__ void cvt3_kernel(const float* __restrict__ x, const float* __restrict__ wa,
                            const float* __restrict__ wp,
                            short* __restrict__ xb, short* __restrict__ wab,
                            short* __restrict__ wpb) {
    int b = blockIdx.x, tid = threadIdx.x;
    const float* src; short* dst; int i;
    if (b < 2048)      { src = x;  dst = xb;  i = b * 256 + tid; }
    else if (b < 2816) { src = wa; dst = wab; i = (b - 2048) * 256 + tid; }
    else               { src = wp; dst = wpb; i = (b - 2816) * 256 + tid; }
    float4 v = ((const float4*)src)[i];
    short4 o;
    o.x = f2bf(v.x); o.y = f2bf(v.y); o.z = f2bf(v.z); o.w = f2bf(v.w);
    ((short4*)dst)[i] = o;
}

// ---------------- GEMM: C[m][n] = sum_k A[m][k] * B[n][k] (B given transposed) ----
// BMxBN tile, BK=64, 256 threads (4 waves 2x2), global_load_lds x16,
// XOR-swizzled LDS, 2-phase double-buffered prefetch (stage t+1 before compute t).
template <int BM, int BN, int OUT_BF16>
__global__ __launch_bounds__(256) void gemm_bt(const short* __restrict__ A,
                                               const short* __restrict__ B,
                                               void* __restrict__ Cv,
                                               int M, int N, int K) {
    __shared__ __align__(16) short As[2][BM][64];
    __shared__ __align__(16) short Bs[2][BN][64];
    constexpr int WM = BM / 2, WN = BN / 2;
    constexpr int MR = WM / 16, NR = WN / 16;
    int bn = blockIdx.x, bm = blockIdx.y;
    int tid = threadIdx.x;
    int lane = tid & 63, w = tid >> 6;
    int wr = w >> 1, wc = w & 1;
    int lr = lane & 15, lg = lane >> 4;

    f32x4 acc[MR][NR];
#pragma unroll
    for (int m = 0; m < MR; ++m)
#pragma unroll
        for (int n = 0; n < NR; ++n) acc[m][n] = f32x4{0.f, 0.f, 0.f, 0.f};

    const short* Ab = A + (size_t)bm * BM * K;
    const short* Bb = B + (size_t)bn * BN * K;

    auto stage = [&](int k0, int b) {
#pragma unroll
        for (int i = 0; i < BM / 32; ++i) {
            int c = i * 256 + tid;
            int row = c >> 3, cb = (c & 7) ^ (row & 7);
            gload_lds16(Ab + (size_t)row * K + k0 + cb * 8, &As[b][0][0] + c * 8);
        }
#pragma unroll
        for (int i = 0; i < BN / 32; ++i) {
            int c = i * 256 + tid;
            int row = c >> 3, cb = (c & 7) ^ (row & 7);
            gload_lds16(Bb + (size_t)row * K + k0 + cb * 8, &Bs[b][0][0] + c * 8);
        }
    };
    auto compute = [&](int b) {
#pragma unroll
        for (int kk = 0; kk < 2; ++kk) {
            s16x8 af[MR], bf[NR];
#pragma unroll
            for (int m = 0; m < MR; ++m) {
                int row = wr * WM + m * 16 + lr;
                af[m] = *(const s16x8*)&As[b][row][(((kk * 4 + lg) ^ (row & 7)) << 3)];
            }
#pragma unroll
            for (int n = 0; n < NR; ++n) {
                int row = wc * WN + n * 16 + lr;
                bf[n] = *(const s16x8*)&Bs[b][row][(((kk * 4 + lg) ^ (row & 7)) << 3)];
            }
#pragma unroll
            for (int m = 0; m < MR; ++m)
#pragma unroll
                for (int n = 0; n < NR; ++n)
                    acc[m][n] = __builtin_amdgcn_mfma_f32_16x16x32_bf16(af[m], bf[n], acc[m][n], 0, 0, 0);
        }
    };

    stage(0, 0);
    __syncthreads();
    int nt = K / 64;
    for (int t = 0; t < nt; ++t) {
        int b = t & 1;
        if (t + 1 < nt) stage((t + 1) * 64, b ^ 1);   // prefetch overlaps compute
        compute(b);
        __syncthreads();
    }

#pragma unroll
    for (int m = 0; m < MR; ++m) {
        int row = bm * BM + wr * WM + m * 16 + lg * 4;
#pragma unroll
        for (int n = 0; n < NR; ++n) {
            int col = bn * BN + wc * WN + n * 16 + lr;
#pragma unroll
            for (int i = 0; i < 4; ++i) {
                size_t idx = (size_t)(row + i) * N + col;
                if (OUT_BF16) ((short*)Cv)[idx] = f2bf(acc[m][n][i]);
                else          ((float*)Cv)[idx] = acc[m][n][i];
            }
        }
    }
}

// ------- fused RoPE (q,k) + V transpose; block = (64 t-rows, head) -------
// q pre-scaled by 0.125 * log2(e): attention runs in exp2 domain.
__global__ __launch_bounds__(256) void prep_kernel(const short* __restrict__ qkv,
                                                   const float* __restrict__ rope,
                                                   short* __restrict__ q,
                                                   short* __restrict__ k,
                                                   short* __restrict__ vt) {
    __shared__ short tile[64][72];
    int bt = blockIdx.x, h = blockIdx.y;
    int tid = threadIdx.x;
    const float QS = 0.18033688011112042f;   // 0.125 * log2(e)

#pragma unroll
    for (int r = 0; r < 2; ++r) {
        int idx = r * 256 + tid;
        int tt = idx >> 3, c8 = idx & 7;
        int t = bt * 64 + tt;
        const short* row = qkv + (size_t)t * (3 * C_) + h * 64 + c8 * 8;
        s16x8 qv = *(const s16x8*)row;
        s16x8 kv = *(const s16x8*)(row + C_);
        float4 rc0 = *(const float4*)(rope + t * 64 + c8 * 8);
        float4 rc1 = *(const float4*)(rope + t * 64 + c8 * 8 + 4);
        float cs[4] = {rc0.x, rc0.z, rc1.x, rc1.z};
        float sn[4] = {rc0.y, rc0.w, rc1.y, rc1.w};
        s16x8 qo, ko;
#pragma unroll
        for (int p = 0; p < 4; ++p) {
            float qe = bf2f(qv[2 * p]), qd = bf2f(qv[2 * p + 1]);
            float ke = bf2f(kv[2 * p]), kd = bf2f(kv[2 * p + 1]);
            qo[2 * p]     = f2bf((qe * cs[p] - qd * sn[p]) * QS);
            qo[2 * p + 1] = f2bf((qd * cs[p] + qe * sn[p]) * QS);
            ko[2 * p]     = f2bf(ke * cs[p] - kd * sn[p]);
            ko[2 * p + 1] = f2bf(kd * cs[p] + ke * sn[p]);
        }
        size_t o = ((size_t)h * T_ + t) * HS_ + c8 * 8;
        *(s16x8*)(q + o) = qo;
        *(s16x8*)(k + o) = ko;
    }

    // V transpose through LDS — vectorized both directions
#pragma unroll
    for (int r = 0; r < 2; ++r) {
        int idx = r * 256 + tid;
        int tt = idx >> 3, c8 = idx & 7;
        *(s16x8*)&tile[tt][c8 * 8] =
            *(const s16x8*)(qkv + (size_t)(bt * 64 + tt) * (3 * C_) + 2 * C_ + h * 64 + c8 * 8);
    }
    __syncthreads();
#pragma unroll
    for (int r = 0; r < 2; ++r) {
        int idx = r * 256 + tid;
        int dd = idx & 63, tg = idx >> 6;   // tg 0..7 across both iters
        s16x8 o;
#pragma unroll
        for (int j = 0; j < 8; ++j) o[j] = tile[tg * 8 + j][dd];
        *(s16x8*)(vt + ((size_t)h * HS_ + dd) * T_ + bt * 64 + tg * 8) = o;
    }
}

// ---------------- Flash attention: constant-M softmax, balanced split-K --------
// Grid = 1152 blocks = 8 heads x 144 (qb,chunk) units; head = bx&7 (XCD pin).
// Per 128-row block qb: tiles = 2qb+2 split into ceil((qb+1)/4) equal chunks.
// Block: 4 waves x 32 rows (2 Q-frags). K,V in LDS (dbuf, XOR-swizzle);
// single per-wave P buffer (A then B frag); l via ones-MFMA.
// p = exp2(s - 12): shift-invariance makes combine a plain sum.
__global__ __launch_bounds__(256) void attn_kernel(const short* __restrict__ q,
                                                   const short* __restrict__ k,
                                                   const short* __restrict__ vt,
                                                   short* __restrict__ ypart,
                                                   float* __restrict__ lpart) {
    __shared__ __align__(16) short Ks[2][64][64];   // 16 KB
    __shared__ __align__(16) short Vs[2][64][64];   // 16 KB
    __shared__ __align__(16) short P[4][16][64];    // 8 KB (A/B reuse)
    int bx = blockIdx.x;
    int h = bx & 7;                    // head -> XCD pin
    int u = bx >> 3;                   // 0..143, heavy qb first
    int qb = 0, j = u;
    for (int qq = 31; qq >= 0; --qq) {
        int ncq = (qq + 4) >> 2;       // ceil((qq+1)/4)
        if (j < ncq) { qb = qq; break; }
        j -= ncq;
    }
    int ncq = (qb + 4) >> 2;
    int tiles = 2 * qb + 2;
    int bas = tiles / ncq, rr = tiles % ncq;
    int t0 = j * bas + (j < rr ? j : rr);
    int t1 = t0 + bas + (j < rr ? 1 : 0);

    int tid = threadIdx.x;
    int w = tid >> 6, lane = tid & 63;
    int lr = lane & 15, lg = lane >> 4, x7 = lane & 7;
    int qrow0 = qb * 128 + w * 32;
    const float MC = 12.0f;            // constant max (log2 domain)

    const short* qp = q + ((size_t)h * T_ + qrow0 + lr) * HS_ + lg * 8;
    s16x8 aq0 = *(const s16x8*)qp;
    s16x8 aq1 = *(const s16x8*)(qp + 32);
    s16x8 aq2 = *(const s16x8*)(qp + 16 * HS_);
    s16x8 aq3 = *(const s16x8*)(qp + 16 * HS_ + 32);

    s16x8 bones;
#pragma unroll
    for (int jj = 0; jj < 8; ++jj) bones[jj] = (short)0x3F80;   // bf16 1.0

    f32x4 yA[4], yB[4];
#pragma unroll
    for (int n = 0; n < 4; ++n) { yA[n] = f32x4{0.f,0.f,0.f,0.f}; yB[n] = f32x4{0.f,0.f,0.f,0.f}; }
    f32x4 lAa = f32x4{0.f,0.f,0.f,0.f}, lBa = f32x4{0.f,0.f,0.f,0.f};

    const short* kH = k + (size_t)h * T_ * HS_;
    const short* vH = vt + (size_t)h * HS_ * T_;

    auto stage = [&](short* Kb, short* Vb, int t) {
#pragma unroll
        for (int r = 0; r < 2; ++r) {
            int c = r * 256 + tid;
            int row = c >> 3;
            int cb = (c & 7) ^ (row & 7);      // inverse-swizzled source col-block
            gload_lds16(kH + (size_t)(t * 64 + row) * HS_ + cb * 8, Kb + c * 8);
            gload_lds16(vH + (size_t)row * T_ + t * 64 + cb * 8, Vb + c * 8);
        }
    };

    short* Pw = &P[w][0][0];

    auto body = [&](int t, const short* Kb, const short* Vb) {
        f32x4 sA[4], sB[4];
#pragma unroll
        for (int c4 = 0; c4 < 4; ++c4) {
            int krow = c4 * 16 + lr;
            const short* kp = Kb + krow * 64;
            s16x8 k0 = *(const s16x8*)(kp + ((lg ^ x7) << 3));
            s16x8 k1 = *(const s16x8*)(kp + (((lg + 4) ^ x7) << 3));
            f32x4 s = f32x4{0.f,0.f,0.f,0.f};
            s = __builtin_amdgcn_mfma_f32_16x16x32_bf16(aq0, k0, s, 0, 0, 0);
            sA[c4] = __builtin_amdgcn_mfma_f32_16x16x32_bf16(aq1, k1, s, 0, 0, 0);
            f32x4 s2 = f32x4{0.f,0.f,0.f,0.f};
            s2 = __builtin_amdgcn_mfma_f32_16x16x32_bf16(aq2, k0, s2, 0, 0, 0);
            sB[c4] = __builtin_amdgcn_mfma_f32_16x16x32_bf16(aq3, k1, s2, 0, 0, 0);
        }
        if (t * 64 + 63 > qrow0) {        // causal mask, frag A (rows qrow0..+15)
#pragma unroll
            for (int c4 = 0; c4 < 4; ++c4) {
                int kcol = t * 64 + c4 * 16 + lr;
#pragma unroll
                for (int i = 0; i < 4; ++i)
                    if (kcol > qrow0 + lg * 4 + i) sA[c4][i] = -1e30f;
            }
        }
        if (t * 64 + 63 > qrow0 + 16) {   // frag B (rows qrow0+16..+31)
#pragma unroll
            for (int c4 = 0; c4 < 4; ++c4) {
                int kcol = t * 64 + c4 * 16 + lr;
#pragma unroll
                for (int i = 0; i < 4; ++i)
                    if (kcol > qrow0 + 16 + lg * 4 + i) sB[c4][i] = -1e30f;
            }
        }
        // V fragments hoisted once (shared by A and B PV)
        s16x8 vf[8];
#pragma unroll
        for (int n = 0; n < 4; ++n) {
            int vrow = n * 16 + lr;
            const short* vrp = Vb + vrow * 64;
            vf[2 * n]     = *(const s16x8*)(vrp + ((lg ^ (vrow & 7)) << 3));
            vf[2 * n + 1] = *(const s16x8*)(vrp + (((lg + 4) ^ (vrow & 7)) << 3));
        }
        // ---- frag A: p = exp2(s-MC) -> P -> A-frag -> l + PV ----
#pragma unroll
        for (int c4 = 0; c4 < 4; ++c4)
#pragma unroll
            for (int i = 0; i < 4; ++i) {
                int row = lg * 4 + i;
                int off = row * 64 + (((c4 * 2 + (lr >> 3)) ^ (row & 7)) << 3) + (lr & 7);
                Pw[off] = f2bf(exp2f(sA[c4][i] - MC));
            }
        s16x8 ap0 = *(const s16x8*)&Pw[lr * 64 + ((lg ^ x7) << 3)];
        s16x8 ap1 = *(const s16x8*)&Pw[lr * 64 + (((lg + 4) ^ x7) << 3)];
        lAa = __builtin_amdgcn_mfma_f32_16x16x32_bf16(ap0, bones, lAa, 0, 0, 0);
        lAa = __builtin_amdgcn_mfma_f32_16x16x32_bf16(ap1, bones, lAa, 0, 0, 0);
#pragma unroll
        for (int n = 0; n < 4; ++n) {
            yA[n] = __builtin_amdgcn_mfma_f32_16x16x32_bf16(ap0, vf[2 * n], yA[n], 0, 0, 0);
            yA[n] = __builtin_amdgcn_mfma_f32_16x16x32_bf16(ap1, vf[2 * n + 1], yA[n], 0, 0, 0);
        }
        // ---- frag B (reuses P buffer) ----
#pragma unroll
        for (int c4 = 0; c4 < 4; ++c4)
#pragma unroll
            for (int i = 0; i < 4; ++i) {
                int row = lg * 4 + i;
                int off = row * 64 + (((c4 * 2 + (lr >> 3)) ^ (row & 7)) << 3) + (lr & 7);
                Pw[off] = f2bf(exp2f(sB[c4][i] - MC));
            }
        s16x8 bp0 = *(const s16x8*)&Pw[lr * 64 + ((lg ^ x7) << 3)];
        s16x8 bp1 = *(const s16x8*)&Pw[lr * 64 + (((lg + 4) ^ x7) << 3)];
        lBa = __builtin_amdgcn_mfma_f32_16x16x32_bf16(bp0, bones, lBa, 0, 0, 0);
        lBa = __builtin_amdgcn_mfma_f32_16x16x32_bf16(bp1, bones, lBa, 0, 0, 0);
#pragma unroll
        for (int n = 0; n < 4; ++n) {
            yB[n] = __builtin_amdgcn_mfma_f32_16x16x32_bf16(bp0, vf[2 * n], yB[n], 0, 0, 0);
            yB[n] = __builtin_amdgcn_mfma_f32_16x16x32_bf16(bp1, vf[2 * n + 1], yB[n], 0, 0, 0);
        }
    };

    // double-buffered pipeline (uniform trip count across waves)
    stage(&Ks[0][0][0], &Vs[0][0][0], t0);
    __syncthreads();
    int t = t0;
    for (;;) {
        bool m1 = (t + 1 < t1);
        if (m1) stage(&Ks[1][0][0], &Vs[1][0][0], t + 1);
        body(t, &Ks[0][0][0], &Vs[0][0][0]);
        __syncthreads();
        ++t;
        if (!m1) break;
        bool m2 = (t + 1 < t1);
        if (m2) stage(&Ks[0][0][0], &Vs[0][0][0], t + 1);
        body(t, &Ks[1][0][0], &Vs[1][0][0]);
        __syncthreads();
        ++t;
        if (!m2) break;
    }

    // write unnormalized bf16 partials + l
    short* yp = ypart + (((size_t)j * H_ + h) * T_ + qrow0) * HS_;
#pragma unroll
    for (int n = 0; n < 4; ++n)
#pragma unroll
        for (int i = 0; i < 4; ++i) {
            yp[(size_t)(lg * 4 + i) * HS_ + n * 16 + lr]      = f2bf(yA[n][i]);
            yp[(size_t)(16 + lg * 4 + i) * HS_ + n * 16 + lr] = f2bf(yB[n][i]);
        }
    if (lr == 0) {
#pragma unroll
        for (int i = 0; i < 4; ++i) {
            size_t r = ((size_t)j * H_ + h) * T_ + qrow0;
            lpart[r + lg * 4 + i]      = lAa[i];
            lpart[r + 16 + lg * 4 + i] = lBa[i];
        }
    }
}

// ---------------- combine partials (plain sums) -> yws bf16 [T][C] ----------------
__global__ void combine_kernel(const short* __restrict__ ypart,
                               const float* __restrict__ lpart,
                               short* __restrict__ y) {
    int g = blockIdx.x * 256 + threadIdx.x;   // 8h * 4096row * 8c8 = 262144
    int c8 = (g & 7) * 8;
    int row = (g >> 3) & 4095;
    int h = g >> 15;
    int nc = ((row >> 7) + 4) >> 2;           // chunks for this row's qb
    float L = 0.f;
    float acc[8] = {0.f, 0.f, 0.f, 0.f, 0.f, 0.f, 0.f, 0.f};
    for (int c = 0; c < nc; ++c) {
        size_t base = ((size_t)c * H_ + h) * T_ + row;
        L += lpart[base];
        s16x8 yv = *(const s16x8*)(ypart + base * HS_ + c8);
#pragma unroll
        for (int jj = 0; jj < 8; ++jj) acc[jj] += bf2f(yv[jj]);
    }
    float inv = 1.f / L;
    s16x8 o;
#pragma unroll
    for (int jj = 0; jj < 8; ++jj) o[jj] = f2bf(acc[jj] * inv);
    *(s16x8*)(y + (size_t)row * C_ + h * 64 + c8) = o;
}

// ---------------- launch ----------------
extern "C" void kernel_launch(void* const* d_in, const int* in_sizes, int n_in,
                              void* d_out, int out_size, void* d_ws, size_t ws_size,
                              hipStream_t stream) {
    const float* x    = (const float*)d_in[0];
    const float* rope = (const float*)d_in[1];
    // d_in[2] = mask (bool) — causality handled analytically
    const float* Wa   = (const float*)d_in[3];
    const float* Wp   = (const float*)d_in[4];
    float* out = (float*)d_out;

    short* ws   = (short*)d_ws;
    short* xb   = ws;                          // 4096*512
    short* wab  = xb + 2097152;                // 1536*512
    short* wpb  = wab + 786432;                // 512*512
    short* qkvb = wpb + 262144;                // 4096*1536
    short* qws  = qkvb + 6291456;              // 8*4096*64
    short* kws  = qws + 2097152;
    short* vtws = kws + 2097152;
    short* yws  = vtws + 2097152;              // 4096*512
    short* ypart = yws + 2097152;              // [8][8][4096][64] bf16 = 33.5 MB
    float* lpart = (float*)(ypart + 16777216); // [8][8][4096] f32 = 1 MB

    cvt3_kernel<<<3072, 256, 0, stream>>>(x, Wa, Wp, xb, wab, wpb);

    gemm_bt<128, 64, 1><<<dim3(24, 32), 256, 0, stream>>>(xb, wab, qkvb, 4096, 1536, 512);

    prep_kernel<<<dim3(64, 8), 256, 0, stream>>>(qkvb, rope, qws, kws, vtws);

    attn_kernel<<<1152, 256, 0, stream>>>(qws, kws, vtws, ypart, lpart);
    combine_kernel<<<1024, 256, 0, stream>>>(ypart, lpart, yws);

    gemm_bt<64, 64, 0><<<dim3(8, 64), 256, 0, stream>>>(yws, wpb, out, 4096, 512, 512);
}

// Round 11
// 169.353 us; speedup vs baseline: 1.1525x; 1.0711x over previous
//
#include <hip/hip_runtime.h>

// Problem constants: B=1, T=4096, C=512, H=8, HS=64
#define T_ 4096
#define C_ 512
#define H_ 8
#define HS_ 64

typedef __attribute__((ext_vector_type(8))) short s16x8;   // 8 x bf16 bits
typedef __attribute__((ext_vector_type(4))) float f32x4;
typedef unsigned int u32;

#if __has_builtin(__builtin_amdgcn_exp2f)
#define EXP2(x) __builtin_amdgcn_exp2f(x)
#else
#define EXP2(x) exp2f(x)
#endif

__device__ __forceinline__ float bf2f(short u) {
    union { float f; unsigned int i; } v;
    v.i = ((unsigned int)(unsigned short)u) << 16;
    return v.f;
}
__device__ __forceinline__ short f2bf(float f) {
    union { float f; unsigned int i; } v;
    v.f = f;
    unsigned int r = (v.i + 0x7FFFu + ((v.i >> 16) & 1u)) >> 16;
    return (short)r;
}
__device__ __forceinline__ short bftrunc(float f) {     // truncating bf16 (P only)
    return (short)(__float_as_uint(f) >> 16);
}

__device__ __forceinline__ void gload_lds16(const short* g, short* l) {
    __builtin_amdgcn_global_load_lds((const __attribute__((address_space(1))) u32*)g,
                                     (__attribute__((address_space(3))) u32*)l,
                                     16, 0, 0);
}

// ---------------- merged f32 -> bf16 convert (x, W_attn, W_proj) ----------------
__global__ void cvt3_kernel(const float* __restrict__ x, const float* __restrict__ wa,
                            const float* __restrict__ wp,
                            short* __restrict__ xb, short* __restrict__ wab,
                            short* __restrict__ wpb) {
    int b = blockIdx.x, tid = threadIdx.x;
    const float* src; short* dst; int i;
    if (b < 2048)      { src = x;  dst = xb;  i = b * 256 + tid; }
    else if (b < 2816) { src = wa; dst = wab; i = (b - 2048) * 256 + tid; }
    else               { src = wp; dst = wpb; i = (b - 2816) * 256 + tid; }
    float4 v = ((const float4*)src)[i];
    short4 o;
    o.x = f2bf(v.x); o.y = f2bf(v.y); o.z = f2bf(v.z); o.w = f2bf(v.w);
    ((short4*)dst)[i] = o;
}

// ------- fused QKV GEMM + RoPE + V-transpose -------
// C[m][n] = sum_k A[m][k] * Wa[n][k]; tile 128x64, BK=64, 4 waves (2x2),
// global_load_lds x16, XOR-swizzled LDS, 2-phase prefetch.
// bn 0..7: q head (RoPE, pre-scaled 0.125*log2e) -> qws[h][t][d]
// bn 8..15: k head (RoPE) -> kws[h][t][d]
// bn 16..23: v head -> transposed via LDS -> vt[h][d][t]
__global__ __launch_bounds__(256) void gemm_qkv(const short* __restrict__ A,
                                                const short* __restrict__ B,
                                                const float* __restrict__ rope,
                                                short* __restrict__ q,
                                                short* __restrict__ k,
                                                short* __restrict__ vt) {
    constexpr int BM = 128, BN = 64, K = 512;
    __shared__ __align__(16) short As[2][BM][64];
    __shared__ __align__(16) short Bs[2][BN][64];
    constexpr int WM = BM / 2, WN = BN / 2;
    constexpr int MR = WM / 16, NR = WN / 16;
    int bn = blockIdx.x, bm = blockIdx.y;
    int tid = threadIdx.x;
    int lane = tid & 63, w = tid >> 6;
    int wr = w >> 1, wc = w & 1;
    int lr = lane & 15, lg = lane >> 4;
    const float QS = 0.18033688011112042f;   // 0.125 * log2(e)

    f32x4 acc[MR][NR];
#pragma unroll
    for (int m = 0; m < MR; ++m)
#pragma unroll
        for (int n = 0; n < NR; ++n) acc[m][n] = f32x4{0.f, 0.f, 0.f, 0.f};

    const short* Ab = A + (size_t)bm * BM * K;
    const short* Bb = B + (size_t)bn * BN * K;

    auto stage = [&](int k0, int b) {
#pragma unroll
        for (int i = 0; i < BM / 32; ++i) {
            int c = i * 256 + tid;
            int row = c >> 3, cb = (c & 7) ^ (row & 7);
            gload_lds16(Ab + (size_t)row * K + k0 + cb * 8, &As[b][0][0] + c * 8);
        }
#pragma unroll
        for (int i = 0; i < BN / 32; ++i) {
            int c = i * 256 + tid;
            int row = c >> 3, cb = (c & 7) ^ (row & 7);
            gload_lds16(Bb + (size_t)row * K + k0 + cb * 8, &Bs[b][0][0] + c * 8);
        }
    };
    auto compute = [&](int b) {
#pragma unroll
        for (int kk = 0; kk < 2; ++kk) {
            s16x8 af[MR], bf[NR];
#pragma unroll
            for (int m = 0; m < MR; ++m) {
                int row = wr * WM + m * 16 + lr;
                af[m] = *(const s16x8*)&As[b][row][(((kk * 4 + lg) ^ (row & 7)) << 3)];
            }
#pragma unroll
            for (int n = 0; n < NR; ++n) {
                int row = wc * WN + n * 16 + lr;
                bf[n] = *(const s16x8*)&Bs[b][row][(((kk * 4 + lg) ^ (row & 7)) << 3)];
            }
#pragma unroll
            for (int m = 0; m < MR; ++m)
#pragma unroll
                for (int n = 0; n < NR; ++n)
                    acc[m][n] = __builtin_amdgcn_mfma_f32_16x16x32_bf16(af[m], bf[n], acc[m][n], 0, 0, 0);
        }
    };

    stage(0, 0);
    __syncthreads();
    constexpr int nt = K / 64;
    for (int t = 0; t < nt; ++t) {
        int b = t & 1;
        if (t + 1 < nt) stage((t + 1) * 64, b ^ 1);
        compute(b);
        __syncthreads();
    }

    int mode = bn >> 3, h = bn & 7;
    if (mode < 2) {
        // RoPE epilogue: pair partner lives in lane^1
        short* dst = mode ? k : q;
        float scl = mode ? 1.0f : QS;
#pragma unroll
        for (int m = 0; m < MR; ++m)
#pragma unroll
            for (int n = 0; n < NR; ++n)
#pragma unroll
                for (int i = 0; i < 4; ++i) {
                    int t = bm * BM + wr * WM + m * 16 + lg * 4 + i;
                    int d = wc * WN + n * 16 + lr;
                    float v = acc[m][n][i];
                    float o = __shfl_xor(v, 1);
                    float2 cs = *(const float2*)(rope + t * 64 + (d & ~1));
                    float out = v * cs.x + ((lr & 1) ? o * cs.y : -o * cs.y);
                    dst[((size_t)h * T_ + t) * HS_ + d] = f2bf(out * scl);
                }
    } else {
        // V: transpose 128t x 64d tile through LDS (As region is free)
        short* tile = &As[0][0][0];           // used as [64][136]
#pragma unroll
        for (int m = 0; m < MR; ++m)
#pragma unroll
            for (int n = 0; n < NR; ++n)
#pragma unroll
                for (int i = 0; i < 4; ++i) {
                    int tl = wr * WM + m * 16 + lg * 4 + i;
                    int d = wc * WN + n * 16 + lr;
                    tile[d * 136 + tl] = f2bf(acc[m][n][i]);
                }
        __syncthreads();
#pragma unroll
        for (int it = 0; it < 2; ++it) {
            int idx = it * 256 + tid;
            int r = idx >> 3, c16 = idx & 7;
            s16x8 a = *(const s16x8*)&tile[r * 136 + c16 * 16];
            s16x8 b = *(const s16x8*)&tile[r * 136 + c16 * 16 + 8];
            short* vp = vt + ((size_t)h * HS_ + r) * T_ + bm * BM + c16 * 16;
            *(s16x8*)vp = a;
            *(s16x8*)(vp + 8) = b;
        }
    }
}

// ---------------- GEMM (proj): C[m][n] = sum_k A[m][k] * B[n][k] ----------------
template <int BM, int BN, int OUT_BF16>
__global__ __launch_bounds__(256) void gemm_bt(const short* __restrict__ A,
                                               const short* __restrict__ B,
                                               void* __restrict__ Cv,
                                               int M, int N, int K) {
    __shared__ __align__(16) short As[2][BM][64];
    __shared__ __align__(16) short Bs[2][BN][64];
    constexpr int WM = BM / 2, WN = BN / 2;
    constexpr int MR = WM / 16, NR = WN / 16;
    int bn = blockIdx.x, bm = blockIdx.y;
    int tid = threadIdx.x;
    int lane = tid & 63, w = tid >> 6;
    int wr = w >> 1, wc = w & 1;
    int lr = lane & 15, lg = lane >> 4;

    f32x4 acc[MR][NR];
#pragma unroll
    for (int m = 0; m < MR; ++m)
#pragma unroll
        for (int n = 0; n < NR; ++n) acc[m][n] = f32x4{0.f, 0.f, 0.f, 0.f};

    const short* Ab = A + (size_t)bm * BM * K;
    const short* Bb = B + (size_t)bn * BN * K;

    auto stage = [&](int k0, int b) {
#pragma unroll
        for (int i = 0; i < BM / 32; ++i) {
            int c = i * 256 + tid;
            int row = c >> 3, cb = (c & 7) ^ (row & 7);
            gload_lds16(Ab + (size_t)row * K + k0 + cb * 8, &As[b][0][0] + c * 8);
        }
#pragma unroll
        for (int i = 0; i < BN / 32; ++i) {
            int c = i * 256 + tid;
            int row = c >> 3, cb = (c & 7) ^ (row & 7);
            gload_lds16(Bb + (size_t)row * K + k0 + cb * 8, &Bs[b][0][0] + c * 8);
        }
    };
    auto compute = [&](int b) {
#pragma unroll
        for (int kk = 0; kk < 2; ++kk) {
            s16x8 af[MR], bf[NR];
#pragma unroll
            for (int m = 0; m < MR; ++m) {
                int row = wr * WM + m * 16 + lr;
                af[m] = *(const s16x8*)&As[b][row][(((kk * 4 + lg) ^ (row & 7)) << 3)];
            }
#pragma unroll
            for (int n = 0; n < NR; ++n) {
                int row = wc * WN + n * 16 + lr;
                bf[n] = *(const s16x8*)&Bs[b][row][(((kk * 4 + lg) ^ (row & 7)) << 3)];
            }
#pragma unroll
            for (int m = 0; m < MR; ++m)
#pragma unroll
                for (int n = 0; n < NR; ++n)
                    acc[m][n] = __builtin_amdgcn_mfma_f32_16x16x32_bf16(af[m], bf[n], acc[m][n], 0, 0, 0);
        }
    };

    stage(0, 0);
    __syncthreads();
    int nt = K / 64;
    for (int t = 0; t < nt; ++t) {
        int b = t & 1;
        if (t + 1 < nt) stage((t + 1) * 64, b ^ 1);
        compute(b);
        __syncthreads();
    }

#pragma unroll
    for (int m = 0; m < MR; ++m) {
        int row = bm * BM + wr * WM + m * 16 + lg * 4;
#pragma unroll
        for (int n = 0; n < NR; ++n) {
            int col = bn * BN + wc * WN + n * 16 + lr;
#pragma unroll
            for (int i = 0; i < 4; ++i) {
                size_t idx = (size_t)(row + i) * N + col;
                if (OUT_BF16) ((short*)Cv)[idx] = f2bf(acc[m][n][i]);
                else          ((float*)Cv)[idx] = acc[m][n][i];
            }
        }
    }
}

// ---------------- Flash attention: constant-M softmax, balanced split-K --------
__global__ __launch_bounds__(256) void attn_kernel(const short* __restrict__ q,
                                                   const short* __restrict__ k,
                                                   const short* __restrict__ vt,
                                                   short* __restrict__ ypart,
                                                   float* __restrict__ lpart) {
    __shared__ __align__(16) short Ks[2][64][64];   // 16 KB
    __shared__ __align__(16) short Vs[2][64][64];   // 16 KB
    __shared__ __align__(16) short P[4][16][64];    // 8 KB (A/B reuse)
    int bx = blockIdx.x;
    int h = bx & 7;                    // head -> XCD pin
    int u = bx >> 3;                   // 0..143, heavy qb first
    int qb = 0, j = u;
    for (int qq = 31; qq >= 0; --qq) {
        int ncq = (qq + 4) >> 2;       // ceil((qq+1)/4)
        if (j < ncq) { qb = qq; break; }
        j -= ncq;
    }
    int ncq = (qb + 4) >> 2;
    int tiles = 2 * qb + 2;
    int bas = tiles / ncq, rr = tiles % ncq;
    int t0 = j * bas + (j < rr ? j : rr);
    int t1 = t0 + bas + (j < rr ? 1 : 0);

    int tid = threadIdx.x;
    int w = tid >> 6, lane = tid & 63;
    int lr = lane & 15, lg = lane >> 4, x7 = lane & 7;
    int qrow0 = qb * 128 + w * 32;
    const float MC = 12.0f;            // constant max (log2 domain)

    const short* qp = q + ((size_t)h * T_ + qrow0 + lr) * HS_ + lg * 8;
    s16x8 aq0 = *(const s16x8*)qp;
    s16x8 aq1 = *(const s16x8*)(qp + 32);
    s16x8 aq2 = *(const s16x8*)(qp + 16 * HS_);
    s16x8 aq3 = *(const s16x8*)(qp + 16 * HS_ + 32);

    s16x8 bones;
#pragma unroll
    for (int jj = 0; jj < 8; ++jj) bones[jj] = (short)0x3F80;   // bf16 1.0

    f32x4 yA[4], yB[4];
#pragma unroll
    for (int n = 0; n < 4; ++n) { yA[n] = f32x4{0.f,0.f,0.f,0.f}; yB[n] = f32x4{0.f,0.f,0.f,0.f}; }
    f32x4 lAa = f32x4{0.f,0.f,0.f,0.f}, lBa = f32x4{0.f,0.f,0.f,0.f};

    const short* kH = k + (size_t)h * T_ * HS_;
    const short* vH = vt + (size_t)h * HS_ * T_;

    auto stage = [&](short* Kb, short* Vb, int t) {
#pragma unroll
        for (int r = 0; r < 2; ++r) {
            int c = r * 256 + tid;
            int row = c >> 3;
            int cb = (c & 7) ^ (row & 7);      // inverse-swizzled source col-block
            gload_lds16(kH + (size_t)(t * 64 + row) * HS_ + cb * 8, Kb + c * 8);
            gload_lds16(vH + (size_t)row * T_ + t * 64 + cb * 8, Vb + c * 8);
        }
    };

    short* Pw = &P[w][0][0];

    auto body = [&](int t, const short* Kb, const short* Vb) {
        f32x4 sA[4], sB[4];
        __builtin_amdgcn_s_setprio(1);
#pragma unroll
        for (int c4 = 0; c4 < 4; ++c4) {
            int krow = c4 * 16 + lr;
            const short* kp = Kb + krow * 64;
            s16x8 k0 = *(const s16x8*)(kp + ((lg ^ x7) << 3));
            s16x8 k1 = *(const s16x8*)(kp + (((lg + 4) ^ x7) << 3));
            f32x4 s = f32x4{0.f,0.f,0.f,0.f};
            s = __builtin_amdgcn_mfma_f32_16x16x32_bf16(aq0, k0, s, 0, 0, 0);
            sA[c4] = __builtin_amdgcn_mfma_f32_16x16x32_bf16(aq1, k1, s, 0, 0, 0);
            f32x4 s2 = f32x4{0.f,0.f,0.f,0.f};
            s2 = __builtin_amdgcn_mfma_f32_16x16x32_bf16(aq2, k0, s2, 0, 0, 0);
            sB[c4] = __builtin_amdgcn_mfma_f32_16x16x32_bf16(aq3, k1, s2, 0, 0, 0);
        }
        __builtin_amdgcn_s_setprio(0);
        if (t * 64 + 63 > qrow0) {        // causal mask, frag A (rows qrow0..+15)
#pragma unroll
            for (int c4 = 0; c4 < 4; ++c4) {
                int kcol = t * 64 + c4 * 16 + lr;
#pragma unroll
                for (int i = 0; i < 4; ++i)
                    if (kcol > qrow0 + lg * 4 + i) sA[c4][i] = -1e30f;
            }
        }
        if (t * 64 + 63 > qrow0 + 16) {   // frag B (rows qrow0+16..+31)
#pragma unroll
            for (int c4 = 0; c4 < 4; ++c4) {
                int kcol = t * 64 + c4 * 16 + lr;
#pragma unroll
                for (int i = 0; i < 4; ++i)
                    if (kcol > qrow0 + 16 + lg * 4 + i) sB[c4][i] = -1e30f;
            }
        }
        // V fragments hoisted once (shared by A and B PV)
        s16x8 vf[8];
#pragma unroll
        for (int n = 0; n < 4; ++n) {
            int vrow = n * 16 + lr;
            const short* vrp = Vb + vrow * 64;
            vf[2 * n]     = *(const s16x8*)(vrp + ((lg ^ (vrow & 7)) << 3));
            vf[2 * n + 1] = *(const s16x8*)(vrp + (((lg + 4) ^ (vrow & 7)) << 3));
        }
        // ---- frag A: p = exp2(s-MC) -> P -> A-frag -> l + PV ----
#pragma unroll
        for (int c4 = 0; c4 < 4; ++c4)
#pragma unroll
            for (int i = 0; i < 4; ++i) {
                int row = lg * 4 + i;
                int off = row * 64 + (((c4 * 2 + (lr >> 3)) ^ (row & 7)) << 3) + (lr & 7);
                Pw[off] = bftrunc(EXP2(sA[c4][i] - MC));
            }
        s16x8 ap0 = *(const s16x8*)&Pw[lr * 64 + ((lg ^ x7) << 3)];
        s16x8 ap1 = *(const s16x8*)&Pw[lr * 64 + (((lg + 4) ^ x7) << 3)];
        __builtin_amdgcn_s_setprio(1);
        lAa = __builtin_amdgcn_mfma_f32_16x16x32_bf16(ap0, bones, lAa, 0, 0, 0);
        lAa = __builtin_amdgcn_mfma_f32_16x16x32_bf16(ap1, bones, lAa, 0, 0, 0);
#pragma unroll
        for (int n = 0; n < 4; ++n) {
            yA[n] = __builtin_amdgcn_mfma_f32_16x16x32_bf16(ap0, vf[2 * n], yA[n], 0, 0, 0);
            yA[n] = __builtin_amdgcn_mfma_f32_16x16x32_bf16(ap1, vf[2 * n + 1], yA[n], 0, 0, 0);
        }
        __builtin_amdgcn_s_setprio(0);
        // ---- frag B (reuses P buffer) ----
#pragma unroll
        for (int c4 = 0; c4 < 4; ++c4)
#pragma unroll
            for (int i = 0; i < 4; ++i) {
                int row = lg * 4 + i;
                int off = row * 64 + (((c4 * 2 + (lr >> 3)) ^ (row & 7)) << 3) + (lr & 7);
                Pw[off] = bftrunc(EXP2(sB[c4][i] - MC));
            }
        s16x8 bp0 = *(const s16x8*)&Pw[lr * 64 + ((lg ^ x7) << 3)];
        s16x8 bp1 = *(const s16x8*)&Pw[lr * 64 + (((lg + 4) ^ x7) << 3)];
        __builtin_amdgcn_s_setprio(1);
        lBa = __builtin_amdgcn_mfma_f32_16x16x32_bf16(bp0, bones, lBa, 0, 0, 0);
        lBa = __builtin_amdgcn_mfma_f32_16x16x32_bf16(bp1, bones, lBa, 0, 0, 0);
#pragma unroll
        for (int n = 0; n < 4; ++n) {
            yB[n] = __builtin_amdgcn_mfma_f32_16x16x32_bf16(bp0, vf[2 * n], yB[n], 0, 0, 0);
            yB[n] = __builtin_amdgcn_mfma_f32_16x16x32_bf16(bp1, vf[2 * n + 1], yB[n], 0, 0, 0);
        }
        __builtin_amdgcn_s_setprio(0);
    };

    // double-buffered pipeline (uniform trip count across waves)
    stage(&Ks[0][0][0], &Vs[0][0][0], t0);
    __syncthreads();
    int t = t0;
    for (;;) {
        bool m1 = (t + 1 < t1);
        if (m1) stage(&Ks[1][0][0], &Vs[1][0][0], t + 1);
        body(t, &Ks[0][0][0], &Vs[0][0][0]);
        __syncthreads();
        ++t;
        if (!m1) break;
        bool m2 = (t + 1 < t1);
        if (m2) stage(&Ks[0][0][0], &Vs[0][0][0], t + 1);
        body(t, &Ks[1][0][0], &Vs[1][0][0]);
        __syncthreads();
        ++t;
        if (!m2) break;
    }

    // write unnormalized bf16 partials + l
    short* yp = ypart + (((size_t)j * H_ + h) * T_ + qrow0) * HS_;
#pragma unroll
    for (int n = 0; n < 4; ++n)
#pragma unroll
        for (int i = 0; i < 4; ++i) {
            yp[(size_t)(lg * 4 + i) * HS_ + n * 16 + lr]      = f2bf(yA[n][i]);
            yp[(size_t)(16 + lg * 4 + i) * HS_ + n * 16 + lr] = f2bf(yB[n][i]);
        }
    if (lr == 0) {
#pragma unroll
        for (int i = 0; i < 4; ++i) {
            size_t r = ((size_t)j * H_ + h) * T_ + qrow0;
            lpart[r + lg * 4 + i]      = lAa[i];
            lpart[r + 16 + lg * 4 + i] = lBa[i];
        }
    }
}

// ---------------- combine partials (plain sums) -> yws bf16 [T][C] ----------------
__global__ void combine_kernel(const short* __restrict__ ypart,
                               const float* __restrict__ lpart,
                               short* __restrict__ y) {
    int g = blockIdx.x * 256 + threadIdx.x;   // 8h * 4096row * 8c8 = 262144
    int c8 = (g & 7) * 8;
    int row = (g >> 3) & 4095;
    int h = g >> 15;
    int nc = ((row >> 7) + 4) >> 2;           // chunks for this row's qb
    float L = 0.f;
    float acc[8] = {0.f, 0.f, 0.f, 0.f, 0.f, 0.f, 0.f, 0.f};
    for (int c = 0; c < nc; ++c) {
        size_t base = ((size_t)c * H_ + h) * T_ + row;
        L += lpart[base];
        s16x8 yv = *(const s16x8*)(ypart + base * HS_ + c8);
#pragma unroll
        for (int jj = 0; jj < 8; ++jj) acc[jj] += bf2f(yv[jj]);
    }
    float inv = 1.f / L;
    s16x8 o;
#pragma unroll
    for (int jj = 0; jj < 8; ++jj) o[jj] = f2bf(acc[jj] * inv);
    *(s16x8*)(y + (size_t)row * C_ + h * 64 + c8) = o;
}

// ---------------- launch ----------------
extern "C" void kernel_launch(void* const* d_in, const int* in_sizes, int n_in,
                              void* d_out, int out_size, void* d_ws, size_t ws_size,
                              hipStream_t stream) {
    const float* x    = (const float*)d_in[0];
    const float* rope = (const float*)d_in[1];
    // d_in[2] = mask (bool) — causality handled analytically
    const float* Wa   = (const float*)d_in[3];
    const float* Wp   = (const float*)d_in[4];
    float* out = (float*)d_out;

    short* ws   = (short*)d_ws;
    short* xb   = ws;                          // 4096*512
    short* wab  = xb + 2097152;                // 1536*512
    short* wpb  = wab + 786432;                // 512*512
    short* qws  = wpb + 262144;                // 8*4096*64
    short* kws  = qws + 2097152;
    short* vtws = kws + 2097152;
    short* yws  = vtws + 2097152;              // 4096*512
    short* ypart = yws + 2097152;              // [8][8][4096][64] bf16 = 33.5 MB
    float* lpart = (float*)(ypart + 16777216); // [8][8][4096] f32 = 1 MB

    cvt3_kernel<<<3072, 256, 0, stream>>>(x, Wa, Wp, xb, wab, wpb);

    gemm_qkv<<<dim3(24, 32), 256, 0, stream>>>(xb, wab, rope, qws, kws, vtws);

    attn_kernel<<<1152, 256, 0, stream>>>(qws, kws, vtws, ypart, lpart);
    combine_kernel<<<1024, 256, 0, stream>>>(ypart, lpart, yws);

    gemm_bt<64, 64, 0><<<dim3(8, 64), 256, 0, stream>>>(yws, wpb, out, 4096, 512, 512);
}